// Round 6
// baseline (343.494 us; speedup 1.0000x reference)
//
#include <hip/hip_runtime.h>
#include <hip/hip_bf16.h>
#include <cstdint>

#define NN   50000
#define EE   800000
#define DIN_ 256
#define HD_  256     // H*DH
#define DH_  64
#define NH_  4
#define NC_  10
#define NG_  100
#define EPS_ 1e-4f
#define SLOPE_ 0.01f
#define AROW 40      // gemm LDS row stride in ushorts (32 data + 8 pad)
#define CAP_ 48      // edge slots per node; P(deg>=48 | Poisson(16)) ~ 1e-12, guarded
#define FROW 264     // agg LDS row stride in ushorts (256 + 8 pad, 16B-aligned: 528B)
#define ZROW 80      // z1b row stride in ushorts (64 + 16 pad, 16B-aligned: 160B)
#define SROW 72      // gemm epilogue scratch row stride in ushorts (64 + 8; 144B)
#define NBLK 3125    // agg blocks

typedef unsigned short ushortT;
typedef __attribute__((ext_vector_type(8))) short short8;
typedef __attribute__((ext_vector_type(4))) float f32x4;

__device__ __forceinline__ float leaky(float x) { return x >= 0.f ? x : SLOPE_ * x; }
__device__ __forceinline__ float sigm(float x)  { return 1.f / (1.f + __expf(-x)); }
__device__ __forceinline__ float b2f(ushortT u) { return __uint_as_float(((unsigned)u) << 16); }
__device__ __forceinline__ ushortT f2b(float f) {            // RNE fp32->bf16
    unsigned u = __float_as_uint(f);
    u += 0x7fffu + ((u >> 16) & 1u);
    return (ushortT)(u >> 16);
}

// ------- setup: cursor + W_feat^T bf16 + W1^T bf16 + W2^T bf16 + group-acc zero -------
__global__ void setup_kernel(int* cursor,
                             const float* __restrict__ W, ushortT* __restrict__ wt,
                             const float* __restrict__ W1, ushortT* __restrict__ w1t,
                             const float* __restrict__ W2, ushortT* __restrict__ w2t,
                             float* __restrict__ gsums, int* __restrict__ gcnt,
                             int* __restrict__ done) {
    int i = blockIdx.x * 256 + threadIdx.x;   // grid covers 65536
    if (i < NN) cursor[i] = 0;
    if (i < DIN_ * HD_) {
        int k = i >> 8, n = i & 255;
        wt[n * DIN_ + k] = f2b(W[i]);
    }
    if (i < 256 * 64) {
        int k = i >> 6, o = i & 63;
        w1t[o * 256 + k] = f2b(W1[i]);
    }
    if (i < 16 * 64) {   // w2t[c][k] = W2[k][c], bf16, cols 10..15 zero
        int c = i >> 6, k = i & 63;
        w2t[i] = (c < NC_) ? f2b(W2[k * NC_ + c]) : (ushortT)0;
    }
    if (i < NG_ * NC_) gsums[i] = 0.f;
    if (i < NG_) gcnt[i] = 0;
    if (i == 0) *done = 0;
}

// ---------------- fused MFMA GEMM + attention scores ----------------
// 512-thread blocks, 128 rows x 256 cols, 1D grid (391 blocks); x read once.
// Epilogue via per-wave LDS transpose (reuses B_lds after a barrier): coalesced
// 16B hbf stores instead of 64 scalar 2B stores/thread.
__global__ __launch_bounds__(512) void gemm_attn(const float* __restrict__ x,
                                                 const ushortT* __restrict__ wt,
                                                 const float* __restrict__ phi,
                                                 ushortT* __restrict__ hbf,
                                                 float* __restrict__ a_s,
                                                 float* __restrict__ a_d) {
    __shared__ ushortT A_lds[128 * AROW];
    __shared__ ushortT B_lds[256 * AROW];   // 10240 ushorts; epilogue scratch needs 8*16*SROW=9216
    const int tid  = threadIdx.x;
    const int wave = tid >> 6, lane = tid & 63;
    const int wm = wave >> 2, wn = wave & 3;   // wm: row half, wn: col quarter (=head)
    const int row0 = blockIdx.x * 128;
    const int q = lane >> 4, l16 = lane & 15;

    f32x4 acc[4][4];
#pragma unroll
    for (int i = 0; i < 4; i++)
#pragma unroll
        for (int j = 0; j < 4; j++) acc[i][j] = (f32x4){0.f, 0.f, 0.f, 0.f};

    const int alm = tid >> 2;           // A row 0..127 (4 threads/row)
    const int alo = (tid & 3) * 8;      // halfword offset 0,8,16,24
    const int blm = tid >> 1;           // B row (=col) 0..255 (2 threads/row)
    const int blo = (tid & 1) * 16;     // halfword offset 0,16

    for (int k0 = 0; k0 < DIN_; k0 += 32) {
        __syncthreads();
        {
            int gr = row0 + alm;
            float4 a0 = make_float4(0.f,0.f,0.f,0.f), a1 = a0;
            if (gr < NN) {
                const float4* xp = (const float4*)(x + (size_t)gr * DIN_ + k0 + alo);
                a0 = xp[0]; a1 = xp[1];
            }
            ushortT* ap = &A_lds[alm * AROW + alo];
            *(ushort4*)(ap + 0) = make_ushort4(f2b(a0.x), f2b(a0.y), f2b(a0.z), f2b(a0.w));
            *(ushort4*)(ap + 4) = make_ushort4(f2b(a1.x), f2b(a1.y), f2b(a1.z), f2b(a1.w));
        }
        {
            const uint4* wp = (const uint4*)(wt + (size_t)blm * DIN_ + k0 + blo);
            uint4 b0 = wp[0], b1 = wp[1];
            *(uint4*)&B_lds[blm * AROW + blo + 0] = b0;
            *(uint4*)&B_lds[blm * AROW + blo + 8] = b1;
        }
        __syncthreads();

        short8 af[4], bf[4];
#pragma unroll
        for (int mi = 0; mi < 4; mi++)
            af[mi] = *(const short8*)&A_lds[(wm * 64 + mi * 16 + l16) * AROW + q * 8];
#pragma unroll
        for (int ni = 0; ni < 4; ni++)
            bf[ni] = *(const short8*)&B_lds[(wn * 64 + ni * 16 + l16) * AROW + q * 8];
#pragma unroll
        for (int mi = 0; mi < 4; mi++)
#pragma unroll
            for (int ni = 0; ni < 4; ni++)
                acc[mi][ni] = __builtin_amdgcn_mfma_f32_16x16x32_bf16(af[mi], bf[ni], acc[mi][ni], 0, 0, 0);
    }

    // ---- epilogue A: hbf store via per-wave LDS transpose ----
    __syncthreads();   // all waves done reading B_lds before scratch reuse
    {
        ushortT* scr = &B_lds[wave * (16 * SROW)];
#pragma unroll
        for (int mi = 0; mi < 4; mi++) {
#pragma unroll
            for (int ni = 0; ni < 4; ni++)
#pragma unroll
                for (int r = 0; r < 4; r++)
                    scr[(q * 4 + r) * SROW + ni * 16 + l16] = f2b(acc[mi][ni][r]);
            int rr = lane >> 2, co = (lane & 3) * 16;
            uint4 v0 = *(const uint4*)&scr[rr * SROW + co];
            uint4 v1 = *(const uint4*)&scr[rr * SROW + co + 8];
            int gr2 = row0 + wm * 64 + mi * 16 + rr;
            if (gr2 < NN) {
                *(uint4*)&hbf[(size_t)gr2 * HD_ + wn * 64 + co]     = v0;
                *(uint4*)&hbf[(size_t)gr2 * HD_ + wn * 64 + co + 8] = v1;
            }
        }
    }

    // ---- epilogue B: attention scores ----
    const int head = wn;
    float phs[4], phd[4];
#pragma unroll
    for (int ni = 0; ni < 4; ni++) {
        phs[ni] = phi[head * 128 + ni * 16 + l16];
        phd[ni] = phi[head * 128 + 64 + ni * 16 + l16];
    }
#pragma unroll
    for (int mi = 0; mi < 4; mi++) {
#pragma unroll
        for (int r = 0; r < 4; r++) {
            float ps = acc[mi][0][r] * phs[0] + acc[mi][1][r] * phs[1]
                     + acc[mi][2][r] * phs[2] + acc[mi][3][r] * phs[3];
            float pd = acc[mi][0][r] * phd[0] + acc[mi][1][r] * phd[1]
                     + acc[mi][2][r] * phd[2] + acc[mi][3][r] * phd[3];
#pragma unroll
            for (int o = 1; o < 16; o <<= 1) {
                ps += __shfl_xor(ps, o);
                pd += __shfl_xor(pd, o);
            }
            if (l16 == 0) {
                int gr = row0 + wm * 64 + mi * 16 + q * 4 + r;
                if (gr < NN) {
                    a_s[gr * 4 + head] = ps;
                    a_d[gr * 4 + head] = pd;
                }
            }
        }
    }
}

// ---------------- fill: direct-slot binning, 16B record {dst, w01, w23, 0} ----------------
// R4-verified: w computed HERE (one sigm set per edge, not per lane — R5's
// in-agg variant was VALU-bound at 64x redundancy).
__global__ void fill_edges(const int* __restrict__ src, const int* __restrict__ dstA,
                           int* __restrict__ cursor,
                           const float* __restrict__ a_s, const float* __restrict__ a_d,
                           uint4* __restrict__ edges) {
    int e = blockIdx.x * 256 + threadIdx.x;
    if (e >= EE) return;
    int s = src[e], d = dstA[e];
    int slot = atomicAdd(&cursor[s], 1);
    if (slot >= CAP_) return;   // statistically impossible; guarded
    float4 as4 = *(const float4*)(a_s + (size_t)s * 4);
    float4 ad4 = *(const float4*)(a_d + (size_t)d * 4);
    unsigned w01 = (unsigned)f2b(sigm(leaky(as4.x + ad4.x)))
                 | ((unsigned)f2b(sigm(leaky(as4.y + ad4.y))) << 16);
    unsigned w23 = (unsigned)f2b(sigm(leaky(as4.z + ad4.z)))
                 | ((unsigned)f2b(sigm(leaky(as4.w + ad4.w))) << 16);
    edges[(size_t)s * CAP_ + slot] = make_uint4((unsigned)d, w01, w23, 0u);
}

// ---------------- FUSED aggregation + MLP + softmax + preds + GROUP MEAN ----------------
// Gather/MFMA phases: R4-verified (65us; at the ~2.8 TB/s random-512B-gather
// regime cap — R2/R3/R5 rewrites all neutral or worse). NEW in v6: group_mean
// kernel eliminated. Block accumulates its 16 nodes' preds into per-group
// partials (batch sorted -> one group per block in the common case -> 10
// atomics/block, ~31 per address), __threadfence + done-counter, last block
// finalizes out[0..1000] = log(sum/cnt) via coherent atomic-reads (device-
// scope atomics; safe under per-XCD L2 non-coherence).
__global__ __launch_bounds__(256) void agg_mlp(const ushortT* __restrict__ hbf,
                                               const int* __restrict__ cursor,
                                               const uint4* __restrict__ edges,
                                               const ushortT* __restrict__ w1t,
                                               const float* __restrict__ b1,
                                               const ushortT* __restrict__ w2t,
                                               const float* __restrict__ b2,
                                               const int* __restrict__ batch,
                                               float* __restrict__ gsums,
                                               int* __restrict__ gcnt,
                                               int* __restrict__ done,
                                               float* __restrict__ out) {
    union ShMem {
        uint4   E[16 * CAP_];     // 12288 B: [local node][slot] edge records
        ushortT A[16 * FROW];     //  8448 B: [local node][dim] bf16 agg, padded
    };
    __shared__ ShMem sh;
    __shared__ ushortT z1b[16 * ZROW];     // [local node][hidden] bf16
    __shared__ int pcnt[16];               // padded edge count per local node
    __shared__ float pb[16][12];           // [local node][class] preds (wave0 only)
    const int tid = threadIdx.x;
    const int wave = tid >> 6, lane = tid & 63;
    const int q = lane >> 4, l16 = lane & 15;
    const int hsel = lane >> 4;
    const int wsh = (hsel & 1) * 16;
    const int n0 = blockIdx.x * 16;        // 3125 * 16 == 50000 exactly
    const ushortT* hrow = hbf + (size_t)lane * 4;

    // ---- phase 0: stage edge records into LDS (coalesced, one load per node) ----
#pragma unroll
    for (int ii = 0; ii < 4; ii++) {
        int ln = wave * 4 + ii;
        int n = n0 + ln;
        int cnt = cursor[n];
        if (cnt > CAP_) cnt = CAP_;
        int pad = (cnt + 7) & ~7;          // multiple of 8; zero-weight filler
        if (lane == 0) pcnt[ln] = pad;
        if (lane < pad) {
            uint4 r = make_uint4(0u, 0u, 0u, 0u);   // dst=0, w=0 -> contributes 0
            if (lane < cnt) r = edges[(size_t)n * CAP_ + lane];
            sh.E[ln * CAP_ + lane] = r;
        }
    }
    __syncthreads();

    // ---- phase 1: gather-accumulate, 8 row-gathers in flight, no tail code ----
    ushort4 o4v[4];
#pragma unroll
    for (int ii = 0; ii < 4; ii++) {
        int ln = wave * 4 + ii;
        int pc = pcnt[ln];
        const uint4* er = &sh.E[ln * CAP_];
        f32x4 acc = (f32x4){0.f, 0.f, 0.f, 0.f};
#pragma unroll 1
        for (int i = 0; i < pc; i += 8) {
            unsigned off[8]; float ww[8];
#pragma unroll
            for (int j = 0; j < 8; j++) {
                uint4 e = er[i + j];                       // LDS broadcast read
                unsigned pair = (hsel & 2) ? e.z : e.y;
                ww[j] = b2f((ushortT)((pair >> wsh) & 0xffffu));
                off[j] = e.x * (unsigned)(HD_ * 2);        // byte offset of row
            }
            ushort4 hh[8];
#pragma unroll
            for (int j = 0; j < 8; j++)
                hh[j] = *(const ushort4*)((const char*)hrow + off[j]);
#pragma unroll
            for (int j = 0; j < 8; j++) {
                acc.x += b2f(hh[j].x) * ww[j];
                acc.y += b2f(hh[j].y) * ww[j];
                acc.z += b2f(hh[j].z) * ww[j];
                acc.w += b2f(hh[j].w) * ww[j];
            }
        }
        o4v[ii] = make_ushort4(f2b(acc.x), f2b(acc.y), f2b(acc.z), f2b(acc.w));
    }
    __syncthreads();   // ALL waves done reading E before anyone overwrites as A

#pragma unroll
    for (int ii = 0; ii < 4; ii++) {
        int ln = wave * 4 + ii;
        *(ushort4*)&sh.A[ln * FROW + lane * 4] = o4v[ii];
    }
    __syncthreads();

    // ---- phase 2: MFMA stage-1. wave = hidden quarter [16*wave, 16*wave+16) ----
    f32x4 macc = (f32x4){0.f, 0.f, 0.f, 0.f};
#pragma unroll
    for (int k0 = 0; k0 < 256; k0 += 32) {
        short8 af = *(const short8*)&sh.A[l16 * FROW + k0 + q * 8];
        short8 bf = *(const short8*)(w1t + (size_t)(wave * 16 + l16) * 256 + k0 + q * 8);
        macc = __builtin_amdgcn_mfma_f32_16x16x32_bf16(af, bf, macc, 0, 0, 0);
    }
    // C layout: col(hidden)=l16, row(node)=q*4+r -> z1b[node][hidden] bf16
    {
        int o = wave * 16 + l16;
        float bb = b1[o];
#pragma unroll
        for (int r = 0; r < 4; r++)
            z1b[(q * 4 + r) * ZROW + o] = f2b(leaky(macc[r] + bb));
    }
    __syncthreads();

    // ---- phase 3: z2 via 2 MFMAs on wave 0 + 16-lane shuffle softmax + group acc ----
    if (wave == 0) {
        f32x4 z2 = (f32x4){0.f, 0.f, 0.f, 0.f};
#pragma unroll
        for (int k0 = 0; k0 < 64; k0 += 32) {
            short8 af = *(const short8*)&z1b[l16 * ZROW + k0 + q * 8]; // A: node=l16
            short8 bf = *(const short8*)(w2t + l16 * 64 + k0 + q * 8); // B: class=l16
            z2 = __builtin_amdgcn_mfma_f32_16x16x32_bf16(af, bf, z2, 0, 0, 0);
        }
        float bb = (l16 < NC_) ? b2[l16] : 0.f;
#pragma unroll
        for (int r = 0; r < 4; r++) {
            float v = (l16 < NC_) ? (z2[r] + bb) : -1e30f;   // col=class, row=q*4+r
            float m = v;
#pragma unroll
            for (int o = 1; o < 16; o <<= 1) m = fmaxf(m, __shfl_xor(m, o));
            float ev = (l16 < NC_) ? (__expf(v - m) + EPS_) : 0.f;
            float s = ev;
#pragma unroll
            for (int o = 1; o < 16; o <<= 1) s += __shfl_xor(s, o);
            if (l16 < NC_) {
                int n = n0 + q * 4 + r;
                float p = ev / s;
                out[1000 + (size_t)n * NC_ + l16] = p;
                pb[q * 4 + r][l16] = p;
            }
        }
        __builtin_amdgcn_wave_barrier();   // order cross-lane pb writes before reads

        // group accumulation (batch sorted; common case: whole block one group)
        int g0  = batch[n0];
        int g15 = batch[n0 + 15];
        if (g0 == g15) {
            if (lane < NC_) {
                float s = 0.f;
#pragma unroll
                for (int n = 0; n < 16; n++) s += pb[n][lane];
                atomicAdd(&gsums[g0 * NC_ + lane], s);
            }
            if (lane == NC_) atomicAdd(&gcnt[g0], 16);
        } else {
            for (int n = 0; n < 16; n++) {
                int g = batch[n0 + n];
                if (lane < NC_) atomicAdd(&gsums[g * NC_ + lane], pb[n][lane]);
                if (lane == NC_) atomicAdd(&gcnt[g], 1);
            }
        }
        __threadfence();   // wave-wide: all lanes' atomics drained before done-add

        int d = 0;
        if (lane == 0) d = atomicAdd(done, 1);
        d = __shfl(d, 0);
        if (d == NBLK - 1) {   // last block finalizes log(group mean)
            for (int i = lane; i < NG_ * NC_; i += 64) {
                int g = i / NC_;
                float sum = atomicAdd(&gsums[i], 0.f);        // coherent read
                int   cn  = atomicAdd(&gcnt[g], 0);
                out[i] = __logf(sum / (float)cn);
            }
        }
    }
}

extern "C" void kernel_launch(void* const* d_in, const int* in_sizes, int n_in,
                              void* d_out, int out_size, void* d_ws, size_t ws_size,
                              hipStream_t stream) {
    const float* x      = (const float*)d_in[0];
    const int*   midx   = (const int*)d_in[1];
    const int*   batch  = (const int*)d_in[2];
    const float* W_feat = (const float*)d_in[3];
    const float* phi    = (const float*)d_in[4];
    const float* W1     = (const float*)d_in[5];
    const float* b1     = (const float*)d_in[6];
    const float* W2     = (const float*)d_in[7];
    const float* b2     = (const float*)d_in[8];
    const int* src = midx;
    const int* dst = midx + EE;
    float* out = (float*)d_out;

    char* p = (char*)d_ws;
    auto alloc = [&](size_t bytes) { void* r = (void*)p; p += (bytes + 255) & ~(size_t)255; return r; };
    ushortT* hbf      = (ushortT*)alloc((size_t)NN * HD_ * 2);
    uint4*   edges    = (uint4*)alloc((size_t)NN * CAP_ * 16);   // 38.4 MB
    ushortT* wt       = (ushortT*)alloc((size_t)DIN_ * HD_ * 2);
    ushortT* w1t      = (ushortT*)alloc((size_t)64 * 256 * 2);
    ushortT* w2t      = (ushortT*)alloc((size_t)16 * 64 * 2);
    float*   a_s      = (float*)alloc((size_t)NN * 4 * 4);
    float*   a_d      = (float*)alloc((size_t)NN * 4 * 4);
    int*     cursor   = (int*)alloc((size_t)NN * 4);
    float*   gsums    = (float*)alloc((size_t)NG_ * NC_ * 4);
    int*     gcnt     = (int*)alloc((size_t)NG_ * 4);
    int*     done     = (int*)alloc((size_t)4);

    setup_kernel<<<256, 256, 0, stream>>>(cursor, W_feat, wt, W1, w1t, W2, w2t,
                                          gsums, gcnt, done);
    gemm_attn<<<(NN + 127) / 128, 512, 0, stream>>>(x, wt, phi, hbf, a_s, a_d);
    fill_edges<<<(EE + 255) / 256, 256, 0, stream>>>(src, dst, cursor, a_s, a_d, edges);
    agg_mlp<<<NN / 16, 256, 0, stream>>>(hbf, cursor, edges, w1t, b1, w2t, b2,
                                         batch, gsums, gcnt, done, out);
}

// Round 7
// 234.310 us; speedup vs baseline: 1.4660x; 1.4660x over previous
//
#include <hip/hip_runtime.h>
#include <hip/hip_bf16.h>
#include <cstdint>

#define NN   50000
#define EE   800000
#define DIN_ 256
#define HD_  256     // H*DH
#define DH_  64
#define NH_  4
#define NC_  10
#define NG_  100
#define EPS_ 1e-4f
#define SLOPE_ 0.01f
#define AROW 40      // gemm LDS row stride in ushorts (32 data + 8 pad)
#define CAP_ 48      // edge slots per node; P(deg>=48 | Poisson(16)) ~ 1e-12, guarded
#define FROW 264     // agg LDS row stride in ushorts (256 + 8 pad, 16B-aligned: 528B)
#define ZROW 80      // z1b row stride in ushorts (64 + 16 pad, 16B-aligned: 160B)
#define SROW 72      // gemm epilogue scratch row stride in ushorts (64 + 8; 144B)

typedef unsigned short ushortT;
typedef __attribute__((ext_vector_type(8))) short short8;
typedef __attribute__((ext_vector_type(4))) float f32x4;

__device__ __forceinline__ float leaky(float x) { return x >= 0.f ? x : SLOPE_ * x; }
__device__ __forceinline__ float sigm(float x)  { return 1.f / (1.f + __expf(-x)); }
__device__ __forceinline__ float b2f(ushortT u) { return __uint_as_float(((unsigned)u) << 16); }
__device__ __forceinline__ ushortT f2b(float f) {            // RNE fp32->bf16
    unsigned u = __float_as_uint(f);
    u += 0x7fffu + ((u >> 16) & 1u);
    return (ushortT)(u >> 16);
}

// ------- setup: cursor + W_feat^T bf16 + W1^T bf16 + W2^T bf16 + gstart -------
__global__ void setup_kernel(int* cursor,
                             const float* __restrict__ W, ushortT* __restrict__ wt,
                             const float* __restrict__ W1, ushortT* __restrict__ w1t,
                             const float* __restrict__ W2, ushortT* __restrict__ w2t,
                             const int* __restrict__ batch, int* __restrict__ gstart) {
    int i = blockIdx.x * 256 + threadIdx.x;   // grid covers 65536
    if (i < NN) {
        cursor[i] = 0;
        int b = batch[i];
        int bp = (i == 0) ? -1 : batch[i - 1];
        for (int g = bp + 1; g <= b; g++) gstart[g] = i;
        if (i == NN - 1) {
            for (int g = b + 1; g <= NG_; g++) gstart[g] = NN;
        }
    }
    if (i < DIN_ * HD_) {
        int k = i >> 8, n = i & 255;
        wt[n * DIN_ + k] = f2b(W[i]);
    }
    if (i < 256 * 64) {
        int k = i >> 6, o = i & 63;
        w1t[o * 256 + k] = f2b(W1[i]);
    }
    if (i < 16 * 64) {   // w2t[c][k] = W2[k][c], bf16, cols 10..15 zero
        int c = i >> 6, k = i & 63;
        w2t[i] = (c < NC_) ? f2b(W2[k * NC_ + c]) : (ushortT)0;
    }
}

// ---------------- fused MFMA GEMM + attention scores ----------------
// 512-thread blocks, 128 rows x 256 cols, 1D grid (391 blocks); x read once.
// v7: K-loop software-pipelined — tile k+1's global loads are ISSUED right
// after the barrier and return while tile k's ds_reads+MFMAs execute, instead
// of the old serial {barrier, load, wait, barrier, MFMA} which put 8 full HBM
// latencies on the critical path. Epilogue: per-wave LDS transpose (verified).
__global__ __launch_bounds__(512) void gemm_attn(const float* __restrict__ x,
                                                 const ushortT* __restrict__ wt,
                                                 const float* __restrict__ phi,
                                                 ushortT* __restrict__ hbf,
                                                 float* __restrict__ a_s,
                                                 float* __restrict__ a_d) {
    __shared__ ushortT A_lds[128 * AROW];
    __shared__ ushortT B_lds[256 * AROW];   // 10240 ushorts; epilogue scratch needs 8*16*SROW=9216
    const int tid  = threadIdx.x;
    const int wave = tid >> 6, lane = tid & 63;
    const int wm = wave >> 2, wn = wave & 3;   // wm: row half, wn: col quarter (=head)
    const int row0 = blockIdx.x * 128;
    const int q = lane >> 4, l16 = lane & 15;

    f32x4 acc[4][4];
#pragma unroll
    for (int i = 0; i < 4; i++)
#pragma unroll
        for (int j = 0; j < 4; j++) acc[i][j] = (f32x4){0.f, 0.f, 0.f, 0.f};

    const int alm = tid >> 2;           // A row 0..127 (4 threads/row)
    const int alo = (tid & 3) * 8;      // halfword offset 0,8,16,24
    const int blm = tid >> 1;           // B row (=col) 0..255 (2 threads/row)
    const int blo = (tid & 1) * 16;     // halfword offset 0,16
    const int gr  = row0 + alm;

    // prologue: tile 0 -> regs
    float4 a0r = make_float4(0.f,0.f,0.f,0.f), a1r = a0r;
    uint4  b0r, b1r;
    if (gr < NN) {
        const float4* xp = (const float4*)(x + (size_t)gr * DIN_ + alo);
        a0r = xp[0]; a1r = xp[1];
    }
    {
        const uint4* wp = (const uint4*)(wt + (size_t)blm * DIN_ + blo);
        b0r = wp[0]; b1r = wp[1];
    }

    for (int k0 = 0; k0 < DIN_; k0 += 32) {
        // write current tile regs -> LDS
        {
            ushortT* ap = &A_lds[alm * AROW + alo];
            *(ushort4*)(ap + 0) = make_ushort4(f2b(a0r.x), f2b(a0r.y), f2b(a0r.z), f2b(a0r.w));
            *(ushort4*)(ap + 4) = make_ushort4(f2b(a1r.x), f2b(a1r.y), f2b(a1r.z), f2b(a1r.w));
            *(uint4*)&B_lds[blm * AROW + blo + 0] = b0r;
            *(uint4*)&B_lds[blm * AROW + blo + 8] = b1r;
        }
        __syncthreads();

        // issue next tile's global loads (overlap with MFMA below)
        if (k0 + 32 < DIN_) {
            a0r = make_float4(0.f,0.f,0.f,0.f); a1r = a0r;
            if (gr < NN) {
                const float4* xp = (const float4*)(x + (size_t)gr * DIN_ + k0 + 32 + alo);
                a0r = xp[0]; a1r = xp[1];
            }
            const uint4* wp = (const uint4*)(wt + (size_t)blm * DIN_ + k0 + 32 + blo);
            b0r = wp[0]; b1r = wp[1];
        }

        short8 af[4], bf[4];
#pragma unroll
        for (int mi = 0; mi < 4; mi++)
            af[mi] = *(const short8*)&A_lds[(wm * 64 + mi * 16 + l16) * AROW + q * 8];
#pragma unroll
        for (int ni = 0; ni < 4; ni++)
            bf[ni] = *(const short8*)&B_lds[(wn * 64 + ni * 16 + l16) * AROW + q * 8];
#pragma unroll
        for (int mi = 0; mi < 4; mi++)
#pragma unroll
            for (int ni = 0; ni < 4; ni++)
                acc[mi][ni] = __builtin_amdgcn_mfma_f32_16x16x32_bf16(af[mi], bf[ni], acc[mi][ni], 0, 0, 0);
        __syncthreads();   // LDS reads done before next iter's writes
    }

    // ---- epilogue A: hbf store via per-wave LDS transpose ----
    {
        ushortT* scr = &B_lds[wave * (16 * SROW)];
#pragma unroll
        for (int mi = 0; mi < 4; mi++) {
#pragma unroll
            for (int ni = 0; ni < 4; ni++)
#pragma unroll
                for (int r = 0; r < 4; r++)
                    scr[(q * 4 + r) * SROW + ni * 16 + l16] = f2b(acc[mi][ni][r]);
            int rr = lane >> 2, co = (lane & 3) * 16;
            uint4 v0 = *(const uint4*)&scr[rr * SROW + co];
            uint4 v1 = *(const uint4*)&scr[rr * SROW + co + 8];
            int gr2 = row0 + wm * 64 + mi * 16 + rr;
            if (gr2 < NN) {
                *(uint4*)&hbf[(size_t)gr2 * HD_ + wn * 64 + co]     = v0;
                *(uint4*)&hbf[(size_t)gr2 * HD_ + wn * 64 + co + 8] = v1;
            }
        }
    }

    // ---- epilogue B: attention scores ----
    const int head = wn;
    float phs[4], phd[4];
#pragma unroll
    for (int ni = 0; ni < 4; ni++) {
        phs[ni] = phi[head * 128 + ni * 16 + l16];
        phd[ni] = phi[head * 128 + 64 + ni * 16 + l16];
    }
#pragma unroll
    for (int mi = 0; mi < 4; mi++) {
#pragma unroll
        for (int r = 0; r < 4; r++) {
            float ps = acc[mi][0][r] * phs[0] + acc[mi][1][r] * phs[1]
                     + acc[mi][2][r] * phs[2] + acc[mi][3][r] * phs[3];
            float pd = acc[mi][0][r] * phd[0] + acc[mi][1][r] * phd[1]
                     + acc[mi][2][r] * phd[2] + acc[mi][3][r] * phd[3];
#pragma unroll
            for (int o = 1; o < 16; o <<= 1) {
                ps += __shfl_xor(ps, o);
                pd += __shfl_xor(pd, o);
            }
            if (l16 == 0) {
                int gr3 = row0 + wm * 64 + mi * 16 + q * 4 + r;
                if (gr3 < NN) {
                    a_s[gr3 * 4 + head] = ps;
                    a_d[gr3 * 4 + head] = pd;
                }
            }
        }
    }
}

// ---------------- fill: direct-slot binning, 16B record {dst, w01, w23, 0} ----------------
// R4-verified: w computed HERE (one sigm set per edge; R5's in-agg variant
// was VALU-bound at 64x lane redundancy).
__global__ void fill_edges(const int* __restrict__ src, const int* __restrict__ dstA,
                           int* __restrict__ cursor,
                           const float* __restrict__ a_s, const float* __restrict__ a_d,
                           uint4* __restrict__ edges) {
    int e = blockIdx.x * 256 + threadIdx.x;
    if (e >= EE) return;
    int s = src[e], d = dstA[e];
    int slot = atomicAdd(&cursor[s], 1);
    if (slot >= CAP_) return;   // statistically impossible; guarded
    float4 as4 = *(const float4*)(a_s + (size_t)s * 4);
    float4 ad4 = *(const float4*)(a_d + (size_t)d * 4);
    unsigned w01 = (unsigned)f2b(sigm(leaky(as4.x + ad4.x)))
                 | ((unsigned)f2b(sigm(leaky(as4.y + ad4.y))) << 16);
    unsigned w23 = (unsigned)f2b(sigm(leaky(as4.z + ad4.z)))
                 | ((unsigned)f2b(sigm(leaky(as4.w + ad4.w))) << 16);
    edges[(size_t)s * CAP_ + slot] = make_uint4((unsigned)d, w01, w23, 0u);
}

// ---------------- FUSED aggregation + MLP + softmax + preds ----------------
// R4-VERIFIED form (65us): LDS-staged 16B records, 8 row-gathers in flight,
// per-node sequential — at the ~2.8 TB/s random-512B-gather fabric cap
// (178MB / 65us; R2/R3/R5/R6 rewrites all neutral or worse). Phase 3: z1
// requantized bf16, z2 = 2 MFMAs on wave 0 + 16-lane shuffle softmax.
// NO device-scope fences/atomics here (R6 lesson: they nuke L2 residency).
__global__ __launch_bounds__(256) void agg_mlp(const ushortT* __restrict__ hbf,
                                               const int* __restrict__ cursor,
                                               const uint4* __restrict__ edges,
                                               const ushortT* __restrict__ w1t,
                                               const float* __restrict__ b1,
                                               const ushortT* __restrict__ w2t,
                                               const float* __restrict__ b2,
                                               float* __restrict__ out) {
    union ShMem {
        uint4   E[16 * CAP_];     // 12288 B: [local node][slot] edge records
        ushortT A[16 * FROW];     //  8448 B: [local node][dim] bf16 agg, padded
    };
    __shared__ ShMem sh;
    __shared__ ushortT z1b[16 * ZROW];     // [local node][hidden] bf16
    __shared__ int pcnt[16];               // padded edge count per local node
    const int tid = threadIdx.x;
    const int wave = tid >> 6, lane = tid & 63;
    const int q = lane >> 4, l16 = lane & 15;
    const int hsel = lane >> 4;
    const int wsh = (hsel & 1) * 16;
    const int n0 = blockIdx.x * 16;        // 3125 * 16 == 50000 exactly
    const ushortT* hrow = hbf + (size_t)lane * 4;

    // ---- phase 0: stage edge records into LDS (coalesced, one load per node) ----
#pragma unroll
    for (int ii = 0; ii < 4; ii++) {
        int ln = wave * 4 + ii;
        int n = n0 + ln;
        int cnt = cursor[n];
        if (cnt > CAP_) cnt = CAP_;
        int pad = (cnt + 7) & ~7;          // multiple of 8; zero-weight filler
        if (lane == 0) pcnt[ln] = pad;
        if (lane < pad) {
            uint4 r = make_uint4(0u, 0u, 0u, 0u);   // dst=0, w=0 -> contributes 0
            if (lane < cnt) r = edges[(size_t)n * CAP_ + lane];
            sh.E[ln * CAP_ + lane] = r;
        }
    }
    __syncthreads();

    // ---- phase 1: gather-accumulate, 8 row-gathers in flight, no tail code ----
    ushort4 o4v[4];
#pragma unroll
    for (int ii = 0; ii < 4; ii++) {
        int ln = wave * 4 + ii;
        int pc = pcnt[ln];
        const uint4* er = &sh.E[ln * CAP_];
        f32x4 acc = (f32x4){0.f, 0.f, 0.f, 0.f};
#pragma unroll 1
        for (int i = 0; i < pc; i += 8) {
            unsigned off[8]; float ww[8];
#pragma unroll
            for (int j = 0; j < 8; j++) {
                uint4 e = er[i + j];                       // LDS broadcast read
                unsigned pair = (hsel & 2) ? e.z : e.y;
                ww[j] = b2f((ushortT)((pair >> wsh) & 0xffffu));
                off[j] = e.x * (unsigned)(HD_ * 2);        // byte offset of row
            }
            ushort4 hh[8];
#pragma unroll
            for (int j = 0; j < 8; j++)
                hh[j] = *(const ushort4*)((const char*)hrow + off[j]);
#pragma unroll
            for (int j = 0; j < 8; j++) {
                acc.x += b2f(hh[j].x) * ww[j];
                acc.y += b2f(hh[j].y) * ww[j];
                acc.z += b2f(hh[j].z) * ww[j];
                acc.w += b2f(hh[j].w) * ww[j];
            }
        }
        o4v[ii] = make_ushort4(f2b(acc.x), f2b(acc.y), f2b(acc.z), f2b(acc.w));
    }
    __syncthreads();   // ALL waves done reading E before anyone overwrites as A

#pragma unroll
    for (int ii = 0; ii < 4; ii++) {
        int ln = wave * 4 + ii;
        *(ushort4*)&sh.A[ln * FROW + lane * 4] = o4v[ii];
    }
    __syncthreads();

    // ---- phase 2: MFMA stage-1. wave = hidden quarter [16*wave, 16*wave+16) ----
    f32x4 macc = (f32x4){0.f, 0.f, 0.f, 0.f};
#pragma unroll
    for (int k0 = 0; k0 < 256; k0 += 32) {
        short8 af = *(const short8*)&sh.A[l16 * FROW + k0 + q * 8];
        short8 bf = *(const short8*)(w1t + (size_t)(wave * 16 + l16) * 256 + k0 + q * 8);
        macc = __builtin_amdgcn_mfma_f32_16x16x32_bf16(af, bf, macc, 0, 0, 0);
    }
    // C layout: col(hidden)=l16, row(node)=q*4+r -> z1b[node][hidden] bf16
    {
        int o = wave * 16 + l16;
        float bb = b1[o];
#pragma unroll
        for (int r = 0; r < 4; r++)
            z1b[(q * 4 + r) * ZROW + o] = f2b(leaky(macc[r] + bb));
    }
    __syncthreads();

    // ---- phase 3: z2 via 2 MFMAs on wave 0 + 16-lane shuffle softmax ----
    if (wave == 0) {
        f32x4 z2 = (f32x4){0.f, 0.f, 0.f, 0.f};
#pragma unroll
        for (int k0 = 0; k0 < 64; k0 += 32) {
            short8 af = *(const short8*)&z1b[l16 * ZROW + k0 + q * 8]; // A: node=l16
            short8 bf = *(const short8*)(w2t + l16 * 64 + k0 + q * 8); // B: class=l16
            z2 = __builtin_amdgcn_mfma_f32_16x16x32_bf16(af, bf, z2, 0, 0, 0);
        }
        float bb = (l16 < NC_) ? b2[l16] : 0.f;
#pragma unroll
        for (int r = 0; r < 4; r++) {
            float v = (l16 < NC_) ? (z2[r] + bb) : -1e30f;   // col=class, row=q*4+r
            float m = v;
#pragma unroll
            for (int o = 1; o < 16; o <<= 1) m = fmaxf(m, __shfl_xor(m, o));
            float ev = (l16 < NC_) ? (__expf(v - m) + EPS_) : 0.f;
            float s = ev;
#pragma unroll
            for (int o = 1; o < 16; o <<= 1) s += __shfl_xor(s, o);
            if (l16 < NC_) {
                int n = n0 + q * 4 + r;
                out[1000 + (size_t)n * NC_ + l16] = ev / s;
            }
        }
    }
}

// ---------------- group mean + log: one block per group, coalesced ----------------
// v7: 320 threads (320 % 10 == 0 -> each thread's stride-320 stream is a
// single class -> scalar accumulator, no runtime-indexed array). Contiguous
// coalesced 4B reads of the group's preds range (old version: 160/256 lanes
// active, 40B strided reads, 154 GB/s, ~13us).
__global__ __launch_bounds__(320) void group_mean(const float* __restrict__ preds,
                                                  const int* __restrict__ gstart,
                                                  float* __restrict__ out) {
    __shared__ float red[320];
    int g = blockIdx.x;
    int t = threadIdx.x;
    int gs = gstart[g], ge = gstart[g + 1];
    const float* base = preds + (size_t)gs * NC_;
    int total = (ge - gs) * NC_;
    float s = 0.f;
    for (int i = t; i < total; i += 320) s += base[i];   // class(base[i]) = i % 10
    red[t] = s;
    __syncthreads();
    if (t < NC_) {
        float tot = 0.f;
#pragma unroll
        for (int j = 0; j < 32; j++) tot += red[t + j * 10];
        out[g * NC_ + t] = __logf(tot / (float)(ge - gs));
    }
}

extern "C" void kernel_launch(void* const* d_in, const int* in_sizes, int n_in,
                              void* d_out, int out_size, void* d_ws, size_t ws_size,
                              hipStream_t stream) {
    const float* x      = (const float*)d_in[0];
    const int*   midx   = (const int*)d_in[1];
    const int*   batch  = (const int*)d_in[2];
    const float* W_feat = (const float*)d_in[3];
    const float* phi    = (const float*)d_in[4];
    const float* W1     = (const float*)d_in[5];
    const float* b1     = (const float*)d_in[6];
    const float* W2     = (const float*)d_in[7];
    const float* b2     = (const float*)d_in[8];
    const int* src = midx;
    const int* dst = midx + EE;
    float* out = (float*)d_out;

    char* p = (char*)d_ws;
    auto alloc = [&](size_t bytes) { void* r = (void*)p; p += (bytes + 255) & ~(size_t)255; return r; };
    ushortT* hbf      = (ushortT*)alloc((size_t)NN * HD_ * 2);
    uint4*   edges    = (uint4*)alloc((size_t)NN * CAP_ * 16);   // 38.4 MB
    ushortT* wt       = (ushortT*)alloc((size_t)DIN_ * HD_ * 2);
    ushortT* w1t      = (ushortT*)alloc((size_t)64 * 256 * 2);
    ushortT* w2t      = (ushortT*)alloc((size_t)16 * 64 * 2);
    float*   a_s      = (float*)alloc((size_t)NN * 4 * 4);
    float*   a_d      = (float*)alloc((size_t)NN * 4 * 4);
    int*     cursor   = (int*)alloc((size_t)NN * 4);
    int*     gstart   = (int*)alloc((size_t)(NG_ + 1) * 4);

    setup_kernel<<<256, 256, 0, stream>>>(cursor, W_feat, wt, W1, w1t, W2, w2t, batch, gstart);
    gemm_attn<<<(NN + 127) / 128, 512, 0, stream>>>(x, wt, phi, hbf, a_s, a_d);
    fill_edges<<<(EE + 255) / 256, 256, 0, stream>>>(src, dst, cursor, a_s, a_d, edges);
    agg_mlp<<<NN / 16, 256, 0, stream>>>(hbf, cursor, edges, w1t, b1, w2t, b2, out);
    group_mean<<<NG_, 320, 0, stream>>>(out + 1000, gstart, out);
}